// Round 4
// baseline (263.541 us; speedup 1.0000x reference)
//
#include <hip/hip_runtime.h>
#include <hip/hip_bf16.h>

// Problem dims (compile-time)
#define SDIM 512   // SEQDIM
#define EDIM 512   // EMBED_DIM
#define LDIM 384   // VFEAT_LEN
#define DDIM 384   // VFEAT_DIM

typedef __attribute__((ext_vector_type(4))) float float4v;

// ---------------------------------------------------------------------------
// Kernel 1: t[e][l] = tanh( sum_k wv[e][k]*v[k][l] + gh[e] ),  gh = wg @ h
// 2-row register tiling + 16-deep load batches. 256 blocks x 384 threads.
// (~10 us; unchanged from R3 — R3 showed this phase is not the bottleneck.)
// ---------------------------------------------------------------------------
__global__ __launch_bounds__(384) void k_tanh_s(
    const float* __restrict__ h, const float* __restrict__ v,
    const float* __restrict__ wv, const float* __restrict__ wg,
    float* __restrict__ t)
{
    const int e0  = blockIdx.x * 2;
    const int tid = threadIdx.x;            // 0..383 = column l
    __shared__ float wvs0[DDIM], wvs1[DDIM];
    __shared__ float red[2][6];

    float g0 = 0.f, g1 = 0.f;
    for (int k = tid; k < SDIM; k += 384) {
        const float hk = h[k];
        g0 += wg[e0 * SDIM + k] * hk;
        g1 += wg[(e0 + 1) * SDIM + k] * hk;
    }
    for (int off = 32; off > 0; off >>= 1) {
        g0 += __shfl_down(g0, off, 64);
        g1 += __shfl_down(g1, off, 64);
    }
    if ((tid & 63) == 0) { red[0][tid >> 6] = g0; red[1][tid >> 6] = g1; }

    wvs0[tid] = wv[e0 * DDIM + tid];
    wvs1[tid] = wv[(e0 + 1) * DDIM + tid];
    __syncthreads();

    const float gh0 = ((red[0][0] + red[0][1]) + (red[0][2] + red[0][3]))
                      + (red[0][4] + red[0][5]);
    const float gh1 = ((red[1][0] + red[1][1]) + (red[1][2] + red[1][3]))
                      + (red[1][4] + red[1][5]);

    const float* vp = v + tid;
    float a[4] = {0.f, 0.f, 0.f, 0.f};
    float b[4] = {0.f, 0.f, 0.f, 0.f};
    for (int kb = 0; kb < DDIM; kb += 16) {   // 24 iters
        float vv[16];
        #pragma unroll
        for (int u = 0; u < 16; ++u)
            vv[u] = vp[(kb + u) * LDIM];
        #pragma unroll
        for (int u = 0; u < 16; ++u) {
            a[u & 3] += wvs0[kb + u] * vv[u];
            b[u & 3] += wvs1[kb + u] * vv[u];
        }
    }
    t[e0 * LDIM + tid]       = tanhf((a[0] + a[1]) + (a[2] + a[3]) + gh0);
    t[(e0 + 1) * LDIM + tid] = tanhf((b[0] + b[1]) + (b[2] + b[3]) + gh1);
}

// ---------------------------------------------------------------------------
// Kernel 2 (FUSED z + softmax + output): one block PAIR per output slice i.
//   z[i][c] = sum_e wh[i][e] * t[e][c]   (each block computes the full row —
//             duplicated across the pair; +302 MB L2 reads, hidden under the
//             store stream of other blocks)
//   alpha   = softmax(z) in-block (shfl + tiny LDS reduce), kept in LDS —
//             no global alpha round-trip, one fewer kernel launch + drain.
//   out[i][j][:] = v[j][:] * alpha[j] for this block's half of the slice
//             (192 j-rows, 294 KB of plain coalesced float4 stores).
// Grid: 768 blocks x 384 threads -> 3 blocks/CU, balanced.
// ---------------------------------------------------------------------------
__global__ __launch_bounds__(384) void k_fused_out(
    const float* __restrict__ wh, const float* __restrict__ t,
    const float* __restrict__ v, float* __restrict__ out)
{
    constexpr int VPS = (LDIM * DDIM) / 4;   // 36864 vec4 per i-slice
    const int i   = blockIdx.x >> 1;         // output slice (0..383)
    const int hlf = blockIdx.x & 1;          // which half of the j-rows
    const int tid = (int)threadIdx.x;        // 0..383 = column c for z-phase

    __shared__ float whs[EDIM];
    __shared__ float al[LDIM];
    __shared__ float redm[6], reds[6];

    for (int e = tid; e < EDIM; e += 384)
        whs[e] = wh[i * EDIM + e];
    __syncthreads();

    // ---- z[c] for c = tid, 16-deep load batches from t (L2-resident) ----
    const float* tp = t + tid;
    float a[4] = {0.f, 0.f, 0.f, 0.f};
    for (int eb = 0; eb < EDIM; eb += 16) {   // 32 iters
        float tv[16];
        #pragma unroll
        for (int u = 0; u < 16; ++u)
            tv[u] = tp[(eb + u) * LDIM];
        #pragma unroll
        for (int u = 0; u < 16; ++u)
            a[u & 3] += whs[eb + u] * tv[u];
    }
    const float z = (a[0] + a[1]) + (a[2] + a[3]);

    // ---- softmax over the 384 columns ----
    float m = z;
    for (int off = 32; off > 0; off >>= 1)
        m = fmaxf(m, __shfl_down(m, off, 64));
    if ((tid & 63) == 0) redm[tid >> 6] = m;
    __syncthreads();
    m = fmaxf(fmaxf(fmaxf(redm[0], redm[1]), fmaxf(redm[2], redm[3])),
              fmaxf(redm[4], redm[5]));

    const float ez = expf(z - m);
    float s = ez;
    for (int off = 32; off > 0; off >>= 1)
        s += __shfl_down(s, off, 64);
    if ((tid & 63) == 0) reds[tid >> 6] = s;
    __syncthreads();
    const float rs = 1.f / (((reds[0] + reds[1]) + (reds[2] + reds[3]))
                            + (reds[4] + reds[5]));
    al[tid] = ez * rs;                        // alpha[i][tid], stays in LDS
    __syncthreads();

    // ---- stream this block's half of out slice i ----
    // 384 threads = 4 j-rows x 96 vec4 per iteration; 48 iters = 192 rows.
    const int jb  = tid / 96;                 // 0..3 (hoisted)
    const int col = tid - jb * 96;            // vec4 column within row
    const int j0  = hlf * (LDIM / 2);         // 0 or 192

    const float4v* v4 = (const float4v*)v;
    float4v* o4 = (float4v*)out + (size_t)i * VPS;

    #pragma unroll 8
    for (int it = 0; it < 48; ++it) {
        const int j   = j0 + it * 4 + jb;
        const int idx = j * 96 + col;         // contiguous across the block
        o4[idx] = v4[idx] * al[j];
    }
}

// ---------------------------------------------------------------------------
extern "C" void kernel_launch(void* const* d_in, const int* in_sizes, int n_in,
                              void* d_out, int out_size, void* d_ws, size_t ws_size,
                              hipStream_t stream)
{
    const float* h  = (const float*)d_in[0];   // (512, 1)   f32
    const float* v  = (const float*)d_in[1];   // (384, 384) f32
    const float* wh = (const float*)d_in[2];   // (384, 512) f32
    const float* wv = (const float*)d_in[3];   // (512, 384) f32
    const float* wg = (const float*)d_in[4];   // (512, 512) f32
    float* out = (float*)d_out;                // (384, 384, 384) f32

    float* t = (float*)d_ws;                   // (512, 384) f32 scratch

    k_tanh_s   <<<EDIM / 2, 384, 0, stream>>>(h, v, wv, wg, t);
    k_fused_out<<<2 * LDIM, 384, 0, stream>>>(wh, t, v, out);
}